// Round 13
// baseline (21667.654 us; speedup 1.0000x reference)
//
#include <hip/hip_runtime.h>

// LayerNorm-LSTM, S=512 B=64 I=H=512 L=2, all I/O f32, all compute f32
// (recurrence is chaotic: bf16 anywhere => absmax ~1.4 FAIL; f32 ordering
//  noise => ~0.016 PASS. f32 VALU only, deterministic orders everywhere.)
//
// Persistent kernel: 256 WGs x 256 thr, 1 WG/CU (141.3 KB LDS).
//   wg = [layer(2)][w(128)]; WG owns rows 0..63 x hc [4w,4w+4) x 4 gates.
//   Per tick: 1024 outputs = [x_t;h](64x1024) @ Wslice(1024x16), W in LDS.
//   R13 GEMM: 8x8 thread tiles, 16 K-groups (64k each), A in 16 chunks of
//   64k double-buffered. LDS-read insts halved vs R12 (was the bottleneck).
// Sync (evolution R8 49ms -> R10 34.6 -> R11 20.3 -> R12 21.6):
//  - h/y0: producers sys-u64 store (at coherence point before release flag);
//    consumers CACHED f32x4 loads gated by acquire-agent fence after the
//    flag wait (R11-proven; L2 amortizes across the XCD's 32 WGs).
//  - LN stats: fixed-point i64 atomicAdd accumulators (integer => exact,
//    order-invariant => deterministic). ONE thin round; parity double-buffer;
//    distributed zeroing ordered via the h-flag release/acquire chain.
//  - flags: phase 2t+1 = stats done, 2t+2 = h/y0 posted. Stats round orders
//    all reads of h/y0/out[t] before any tick-t writes (race-freedom proof
//    unchanged from R8-R12).

#define NTH 256

typedef float f32x4 __attribute__((ext_vector_type(4)));

__device__ __forceinline__ float sigm(float x) { return 1.f / (1.f + __expf(-x)); }
__device__ __forceinline__ float tanh_f(float x) { return 2.f / (1.f + __expf(-2.f * x)) - 1.f; }

__device__ __forceinline__ void sys_store64(unsigned long long* p, unsigned long long v) {
  __hip_atomic_store(p, v, __ATOMIC_RELAXED, __HIP_MEMORY_SCOPE_SYSTEM);
}
__device__ __forceinline__ unsigned long long sys_load64(const unsigned long long* p) {
  return __hip_atomic_load(p, __ATOMIC_RELAXED, __HIP_MEMORY_SCOPE_SYSTEM);
}
__device__ __forceinline__ unsigned long long pack2(float a, float b) {
  union { float f[2]; unsigned long long u; } x; x.f[0] = a; x.f[1] = b; return x.u;
}

// post: __syncthreads drains all threads' prior mem ops, then single-writer
// RELEASE store of the phase value (orders atomics/stores before the flag).
__device__ __forceinline__ void post(unsigned int* flag, unsigned int val) {
  __syncthreads();
  if (threadIdx.x == 0)
    __hip_atomic_store(flag, val, __ATOMIC_RELEASE, __HIP_MEMORY_SCOPE_SYSTEM);
}

// waitall: until flags[i*32] >= target for all i<128.
__device__ __forceinline__ void waitall(const unsigned int* flags, unsigned int target) {
  long guard = 0;
  for (;;) {
    int ok = 1;
    if (threadIdx.x < 128) {
      unsigned int v = __hip_atomic_load(&flags[threadIdx.x * 32],
                                         __ATOMIC_RELAXED, __HIP_MEMORY_SCOPE_SYSTEM);
      ok = (v >= target);
    }
    if (__syncthreads_and(ok)) break;
    if (++guard > (1L << 22)) break;   // safety valve; never hit when healthy
  }
  __atomic_signal_fence(__ATOMIC_ACQUIRE);
}

__global__ __launch_bounds__(NTH, 1)
void lstm_pk(const float* __restrict__ inputs, const float* __restrict__ h0,
             const float* __restrict__ c0,
             const float* __restrict__ wx0, const float* __restrict__ wx1,
             const float* __restrict__ wh0, const float* __restrict__ wh1,
             const float* __restrict__ bias, const float* __restrict__ gamma_,
             const float* __restrict__ beta_,
             float* __restrict__ out,
             unsigned int* flags,               // [2][128][32] u32
             unsigned long long* stat_ws,       // [2 parity][2 layer][256][2] i64
             float* __restrict__ h_state)       // [2][64][512] f32
{
  extern __shared__ float lds[];
  float* W_lds = lds;                   // [1024][16]      16384 f = 64 KB
  float* A_lds = lds + 16384;           // [2][64][68]      8704 f = 34.8 KB
  float* part  = lds + 16384 + 8704;    // [8][64][17]      8704 f = 34.8 KB
  float* gates = part + 8704;           // [64][16]         1024 f =  4 KB
  float* minv  = gates + 1024;          // [256 pair][2]     512 f =  2 KB
  // total 35328 floats = 141312 B

  const int tid = threadIdx.x;
  const int wg = blockIdx.x;
  const int layer = wg >> 7;
  const int w = wg & 127;            // hc slice [4w, 4w+4)
  // 8x8 GEMM tiling ids:
  const int cb = tid & 1;            // col octet: cols 8cb..8cb+7
  const int ra = (tid >> 1) & 7;     // row octet: rows 8ra..8ra+7
  const int m  = tid >> 4;           // K-group 0..15 (4 k per 64k-chunk)
  // staging ids:
  const int strow = tid & 63;        // row this thread stages
  const int kq4 = tid >> 6;          // k-quad set 0..3
  // epilogue/cell ids:
  const int srow = tid >> 2;         // row 0..63
  const int sg = tid & 3;            // stats: gate; cell: hc-within-slice
  const int hc = 4 * w + sg;         // global h column (cell phase)

  const float* Wx = layer ? wx1 : wx0;
  const float* Wh = layer ? wh1 : wh0;

  // ---- one-time: W slice -> LDS. W_lds[k][g*4+j] = W[k][g*512+4w+j]
  for (int i = 0; i < 16; ++i) {
    int e = tid + i * 256;           // [0,4096)
    int k = e >> 2, g = e & 3;
    const float* src = (k < 512) ? (Wx + (size_t)k * 2048)
                                 : (Wh + (size_t)(k - 512) * 2048);
    f32x4 v = *(const f32x4*)(src + g * 512 + 4 * w);
    *(f32x4*)&W_lds[k * 16 + g * 4] = v;
  }

  f32x4 biasr = *(const f32x4*)(bias + layer * 2048 + sg * 512 + 4 * w);
  float gam[4], bet[4];
#pragma unroll
  for (int g = 0; g < 4; ++g) {
    gam[g] = gamma_[layer * 2048 + g * 512 + hc];
    bet[g] = beta_[layer * 2048 + g * 512 + hc];
  }
  float c_st = c0[layer * 32768 + srow * 512 + hc];

  float* hstL = h_state + layer * 32768;
  unsigned int* fmyL = flags + layer * 4096;     // my layer's 128 flags
  unsigned int* myflag = fmyL + w * 32;
  const unsigned int* fL0 = flags;               // layer-0 flags

  const int first = layer ? 8 : 0;               // L1: h-half first

  for (int t = 0; t < 512; ++t) {
    const unsigned int t2 = 2u * (unsigned)t;
    const float* xsrc = (layer ? out : inputs) + (size_t)t * 32768;
    const float* hsrc = (t == 0) ? (h0 + layer * 32768) : hstL;
    unsigned long long* statbuf = stat_ws + ((size_t)(t & 1) * 2 + layer) * 512;

    // L1 starts with the h-half: own h(t-1) must be posted & visible.
    if (layer == 1) {
      waitall(fmyL, t2);
      __builtin_amdgcn_fence(__ATOMIC_ACQUIRE, "agent");
    }

    f32x4 acc[8][2];
#pragma unroll
    for (int r = 0; r < 8; ++r) {
      acc[r][0] = (f32x4){0.f, 0.f, 0.f, 0.f};
      acc[r][1] = (f32x4){0.f, 0.f, 0.f, 0.f};
    }

    f32x4 st[4];
    auto LOADC = [&](int c) {            // chunk c: c>=8 -> h, else x (64 k)
      const float* src = (c >= 8) ? (hsrc + strow * 512 + (c - 8) * 64)
                                  : (xsrc + strow * 512 + c * 64);
#pragma unroll
      for (int i = 0; i < 4; ++i)
        st[i] = *(const f32x4*)(src + 4 * (kq4 + 4 * i));
    };
    auto WRITEC = [&](int b) {           // regs -> A_lds[b], [k][row]
      float* dst = A_lds + b * 4352;
#pragma unroll
      for (int i = 0; i < 4; ++i) {
        int kk = 4 * (kq4 + 4 * i);
#pragma unroll
        for (int j = 0; j < 4; ++j)
          dst[(kk + j) * 68 + strow] = st[i][j];
      }
    };
    auto COMPUTEC = [&](int c, int b) {
      const float* Ab = A_lds + b * 4352;
      const int kW = (c < 8 ? c * 64 : 512 + (c - 8) * 64) + 4 * m;
      const int kA = 4 * m;
#pragma unroll
      for (int kk = 0; kk < 4; ++kk) {
        const float* arow = &Ab[(kA + kk) * 68 + 8 * ra];
        f32x4 av0 = *(const f32x4*)arow;
        f32x4 av1 = *(const f32x4*)(arow + 4);
        const float* wrow = &W_lds[(kW + kk) * 16 + 8 * cb];
        f32x4 wv0 = *(const f32x4*)wrow;
        f32x4 wv1 = *(const f32x4*)(wrow + 4);
#pragma unroll
        for (int r = 0; r < 4; ++r) {
          acc[r][0] += av0[r] * wv0;
          acc[r][1] += av0[r] * wv1;
          acc[r + 4][0] += av1[r] * wv0;
          acc[r + 4][1] += av1[r] * wv1;
        }
      }
    };

    LOADC(first);
    WRITEC(0);
    __syncthreads();
#pragma unroll 1
    for (int co = 0; co < 16; ++co) {
      int c = (co + first) & 15;
      if (co < 15) {
        if (co == 7) {
          // about to prefetch the other half's first chunk
          if (layer == 1) {              // x-half = y0(t): L0 posted 2t+2
            waitall(fL0, t2 + 2u);
            __builtin_amdgcn_fence(__ATOMIC_ACQUIRE, "agent");
          } else {                       // h-half: own h(t-1) posted
            waitall(fmyL, t2);
            __builtin_amdgcn_fence(__ATOMIC_ACQUIRE, "agent");
          }
        }
        LOADC((c + 1) & 15);
      }
      COMPUTEC(c, co & 1);
      if (co < 15) WRITEC((co + 1) & 1);
      __syncthreads();
    }

    // ---- two-stage K-group merge (16 -> 8 in LDS)
    if (m >= 8) {
      float* pg = part + (size_t)(m - 8) * 1088;
#pragma unroll
      for (int r = 0; r < 8; ++r) {
        *(f32x4*)&pg[(8 * ra + r) * 17 + 8 * cb] = acc[r][0];
        *(f32x4*)&pg[(8 * ra + r) * 17 + 8 * cb + 4] = acc[r][1];
      }
    }
    __syncthreads();
    if (m < 8) {
      float* pg = part + (size_t)m * 1088;
#pragma unroll
      for (int r = 0; r < 8; ++r) {
        float* p0 = &pg[(8 * ra + r) * 17 + 8 * cb];
        f32x4 v0 = *(f32x4*)p0 + acc[r][0];
        f32x4 v1 = *(f32x4*)(p0 + 4) + acc[r][1];
        *(f32x4*)p0 = v0;
        *(f32x4*)(p0 + 4) = v1;
      }
    }
    __syncthreads();

    // ---- final 8-group sum + bias -> gates; fixed-point stats atomics
    {
      f32x4 pre = biasr;
#pragma unroll
      for (int g = 0; g < 8; ++g)
        pre += *(const f32x4*)&part[(size_t)g * 1088 + srow * 17 + sg * 4];
      *(f32x4*)&gates[srow * 16 + sg * 4] = pre;
      float s = ((pre[0] + pre[1]) + pre[2]) + pre[3];
      float ss = ((pre[0] * pre[0] + pre[1] * pre[1]) + pre[2] * pre[2]) + pre[3] * pre[3];
      atomicAdd(&statbuf[2 * tid],
                (unsigned long long)(long long)llrintf(s * 1048576.f));
      atomicAdd(&statbuf[2 * tid + 1],
                (unsigned long long)(long long)llrintf(ss * 1048576.f));
    }
    post(myflag, t2 + 1u);               // stats complete
    waitall(fmyL, t2 + 1u);

    // zero the other parity buffer (last read at t-1; ordering rides the
    // h-flag chain: zero -> post h(t) -> consumers acquire before t+1 adds)
    {
      unsigned long long* zb = stat_ws + ((size_t)((t + 1) & 1) * 2 + layer) * 512;
      if (tid < 4) sys_store64(&zb[4 * w + tid], 0ull);
    }

    // read accumulators (sys, at coherence point), minv -> LDS
    {
      long long S = (long long)sys_load64(&statbuf[2 * tid]);
      long long SS = (long long)sys_load64(&statbuf[2 * tid + 1]);
      float Sf = (float)S * (1.f / 1048576.f);
      float SSf = (float)SS * (1.f / 1048576.f);
      float mu = Sf * (1.f / 512.f);
      float var = SSf * (1.f / 512.f) - mu * mu;
      minv[2 * tid + 0] = mu;
      minv[2 * tid + 1] = rsqrtf(fmaxf(var, 0.f) + 1e-5f);
    }
    __syncthreads();

    // normalize + cell (thread owns (srow, hc))
    {
      float gv[4];
#pragma unroll
      for (int g = 0; g < 4; ++g) {
        float pre = gates[srow * 16 + g * 4 + sg];
        gv[g] = (pre - minv[(srow * 4 + g) * 2]) * minv[(srow * 4 + g) * 2 + 1] * gam[g] + bet[g];
      }
      float ig = sigm(gv[0]);
      float fg = sigm(gv[1]);
      float og = sigm(gv[2]);
      float ug = tanh_f(gv[3]);
      c_st = fg * c_st + ig * ug;
      float hv = og * tanh_f(c_st);

      // pair-pack (even sg stores {sg, sg+1}); SYSTEM-store h and y
      float hv2 = __shfl_down(hv, 1);
      float cv2 = __shfl_down(c_st, 1);
      if ((sg & 1) == 0) {
        unsigned long long hp = pack2(hv, hv2);
        sys_store64((unsigned long long*)&hstL[srow * 512 + hc], hp);
        sys_store64((unsigned long long*)&out[(size_t)t * 32768 + srow * 512 + hc], hp);
        if (t == 511) {
          sys_store64((unsigned long long*)&out[16777216 + layer * 32768 + srow * 512 + hc], hp);
          sys_store64((unsigned long long*)&out[16842752 + layer * 32768 + srow * 512 + hc],
                      pack2(c_st, cv2));
        }
      }
    }
    post(myflag, t2 + 2u);               // h / y0 posted
  }
}

extern "C" void kernel_launch(void* const* d_in, const int* in_sizes, int n_in,
                              void* d_out, int out_size, void* d_ws, size_t ws_size,
                              hipStream_t stream) {
  const float* inputs = (const float*)d_in[0];
  const float* h0 = (const float*)d_in[1];
  const float* c0 = (const float*)d_in[2];
  const float* wx0 = (const float*)d_in[3];
  const float* wx1 = (const float*)d_in[4];
  const float* wh0 = (const float*)d_in[5];
  const float* wh1 = (const float*)d_in[6];
  const float* bias = (const float*)d_in[7];
  const float* gamma_ = (const float*)d_in[8];
  const float* beta_ = (const float*)d_in[9];
  float* out = (float*)d_out;

  char* ws = (char*)d_ws;
  unsigned int* flags = (unsigned int*)ws;                         // 32 KB (64K pad)
  unsigned long long* stat_ws = (unsigned long long*)(ws + 65536); // 16 KB
  float* h_state = (float*)(ws + 65536 + 16384);                   // 256 KB

  const int smem_bytes = 141312;
  hipFuncSetAttribute((const void*)lstm_pk,
                      hipFuncAttributeMaxDynamicSharedMemorySize, smem_bytes);
  hipMemsetAsync(ws, 0, 65536 + 16384, stream);   // zero flags + stat bufs

  hipLaunchKernelGGL(lstm_pk, dim3(256), dim3(NTH), smem_bytes, stream,
                     inputs, h0, c0, wx0, wx1, wh0, wh1, bias, gamma_, beta_,
                     out, flags, stat_ws, h_state);
}